// Round 2
// baseline (1117.178 us; speedup 1.0000x reference)
//
#include <hip/hip_runtime.h>

#define SEQ   2048
#define HD    128
#define BN    64
#define NITER (SEQ / BN)

typedef __fp16 f16x8  __attribute__((ext_vector_type(8)));
typedef float  f32x4  __attribute__((ext_vector_type(4)));
typedef float  f32x16 __attribute__((ext_vector_type(16)));

// pack two fp32 -> one uint of two f16 (RTZ)
__device__ __forceinline__ unsigned pkh(float a, float b) {
  auto h = __builtin_amdgcn_cvt_pkrtz(a, b);
  return __builtin_bit_cast(unsigned, h);
}

__global__ __launch_bounds__(256, 4)
void fa_gqa_kernel(const float* __restrict__ Q,
                   const float* __restrict__ K,
                   const float* __restrict__ V,
                   float* __restrict__ O)
{
  // K tile [64 k][128 d] f16; 16B chunk j at position j ^ (row&15)
  __shared__ unsigned short kt_lds[64 * HD];
  // V^T tile [128 d][64 k] f16; 16B chunk c8 (8 k) at pos c8 ^ (((d>>3)^d)&7)
  __shared__ unsigned short vt_lds[HD * 64];

  const int tid  = threadIdx.x;
  const int lane = tid & 63;
  const int w    = tid >> 6;
  const int ml   = lane & 31;   // 32x32 MFMA row/col lane index
  const int hi   = lane >> 5;   // half-wave select
  const bool hib = (hi != 0);

  // XCD-clustered virtual block mapping (K/V L2 locality)
  const int F     = blockIdx.x;        // 0..1023
  const int xcd   = F & 7;
  const int s     = F >> 3;
  const int bh    = xcd * 8 + (s >> 4);
  const int qtile = s & 15;

  const int b = bh >> 5;
  const int h = bh & 31;
  const long qrow0 = (long)bh * SEQ + qtile * 128 + w * 32;
  const float* Qw = Q + qrow0 * HD;
  float*       Ow = O + qrow0 * HD;
  const long kvoff = (long)(b * 8 + (h >> 2)) * SEQ * HD;
  const float* Kb = K + kvoff;
  const float* Vb = V + kvoff;

  // Q fragments (B-operand of 32x32x16: lane holds Q[q=w*32+ml][d=dc*16+hi*8+j])
  f16x8 qf[8];
#pragma unroll
  for (int dc = 0; dc < 8; ++dc) {
    const float4* qp = (const float4*)(Qw + ml * HD + dc * 16 + hi * 8);
    float4 a = qp[0], bq = qp[1];
    int4 t;
    t.x = (int)pkh(a.x, a.y);
    t.y = (int)pkh(a.z, a.w);
    t.z = (int)pkh(bq.x, bq.y);
    t.w = (int)pkh(bq.z, bq.w);
    qf[dc] = __builtin_bit_cast(f16x8, t);
  }

  // O^T accumulators: 4 d-tiles of 32x32; lane holds O[q=ml][d=dt*32+(r&3)+8(r>>2)+4hi]
  f32x16 oacc[4];
#pragma unroll
  for (int dt = 0; dt < 4; ++dt)
    oacc[dt] = (f32x16)(0.f);

  float mst = -1e30f;
  float lst = 0.f;

  const float K1 = 0.08838834764831845f * 1.4426950408889634f; // scale*log2(e)

  // staging roles
  const int krow = tid >> 2;      // K: 0..63
  const int kq4  = tid & 3;       // K: 32-float quarter of the row
  const int kq   = tid >> 4;      // V: k-quad 0..15 (rows 4kq..4kq+3)
  const int dc8  = tid & 15;      // V: 8-float d chunk

  for (int it = 0; it < NITER; ++it) {
    const int k0 = it * BN;

    // ---- global loads + cvt to f16 (pre-barrier) ----
    const float* kp = Kb + (long)(k0 + krow) * HD + kq4 * 32;
    int4 ks[4];
#pragma unroll
    for (int jj = 0; jj < 4; ++jj) {
      float4 e = ((const float4*)kp)[2 * jj];
      float4 o = ((const float4*)kp)[2 * jj + 1];
      ks[jj].x = (int)pkh(e.x, e.y);
      ks[jj].y = (int)pkh(e.z, e.w);
      ks[jj].z = (int)pkh(o.x, o.y);
      ks[jj].w = (int)pkh(o.z, o.w);
    }

    const float* vp = Vb + (long)(k0 + 4 * kq) * HD + dc8 * 8;
    float4 vr[4][2];
#pragma unroll
    for (int r = 0; r < 4; ++r) {
      vr[r][0] = ((const float4*)(vp + r * HD))[0];
      vr[r][1] = ((const float4*)(vp + r * HD))[1];
    }
    uint2 vs[8];
#pragma unroll
    for (int jd = 0; jd < 8; ++jd) {
      const int hsel = jd >> 2, e = jd & 3;
      float x0 = ((const float*)&vr[0][hsel])[e];
      float x1 = ((const float*)&vr[1][hsel])[e];
      float x2 = ((const float*)&vr[2][hsel])[e];
      float x3 = ((const float*)&vr[3][hsel])[e];
      vs[jd].x = pkh(x0, x1);
      vs[jd].y = pkh(x2, x3);
    }

    __syncthreads();  // (A) all waves done reading prev tiles

    // K staging: 4 swizzled b128 stores
#pragma unroll
    for (int jj = 0; jj < 4; ++jj) {
      int j = kq4 * 4 + jj;
      int pos = j ^ (krow & 15);
      *(int4*)(kt_lds + krow * HD + pos * 8) = ks[jj];
    }
    // V^T staging: 8 swizzled b64 stores; 16B chunk (kq>>1) at pos ^ sw3(d)
#pragma unroll
    for (int jd = 0; jd < 8; ++jd) {
      int d = dc8 * 8 + jd;
      int sw3 = ((d >> 3) ^ d) & 7;
      int pos = (kq >> 1) ^ sw3;
      *(uint2*)(vt_lds + d * 64 + pos * 8 + (kq & 1) * 4) = vs[jd];
    }

    __syncthreads();  // (B) staging visible

    // ---- S^T = K * Q^T (32x32x16): lane holds S[q=ml][k=kt*32+(r&3)+8(r>>2)+4hi] ----
    f32x16 sacc[2];
    sacc[0] = (f32x16)(0.f);
    sacc[1] = (f32x16)(0.f);

    __builtin_amdgcn_s_setprio(1);
#pragma unroll
    for (int dc = 0; dc < 8; ++dc) {
#pragma unroll
      for (int kt = 0; kt < 2; ++kt) {
        int row = kt * 32 + ml;
        int pos = (2 * dc + hi) ^ (row & 15);
        f16x8 af = *(const f16x8*)(kt_lds + row * HD + pos * 8);
        sacc[kt] = __builtin_amdgcn_mfma_f32_32x32x16_f16(
            af, qf[dc], sacc[kt], 0, 0, 0);
      }
    }
    __builtin_amdgcn_s_setprio(0);

    // ---- online softmax: one q-column per lane ----
    // 4-way parallel max chains (~4x less dep depth than serial)
    float x0 = fmaxf(sacc[0][0], sacc[1][0]);
    float x1 = fmaxf(sacc[0][1], sacc[1][1]);
    float x2 = fmaxf(sacc[0][2], sacc[1][2]);
    float x3 = fmaxf(sacc[0][3], sacc[1][3]);
#pragma unroll
    for (int r = 4; r < 16; r += 4) {
      x0 = fmaxf(x0, fmaxf(sacc[0][r + 0], sacc[1][r + 0]));
      x1 = fmaxf(x1, fmaxf(sacc[0][r + 1], sacc[1][r + 1]));
      x2 = fmaxf(x2, fmaxf(sacc[0][r + 2], sacc[1][r + 2]));
      x3 = fmaxf(x3, fmaxf(sacc[0][r + 3], sacc[1][r + 3]));
    }
    float mx = fmaxf(fmaxf(x0, x1), fmaxf(x2, x3));
    mx = fmaxf(mx, __shfl_xor(mx, 32, 64));  // proven cross-half reduce

    // defer-max: skip rescale when running max unchanged (alpha would be exactly 1)
    if (__any(mx > mst)) {
      float mnew = fmaxf(mst, mx);
      float alpha = __builtin_amdgcn_exp2f(K1 * (mst - mnew));
      mst = mnew;
      lst *= alpha;
#pragma unroll
      for (int dt = 0; dt < 4; ++dt)
        oacc[dt] *= alpha;
    }

    const float nm = -K1 * mst;
    float p0 = 0.f, p1 = 0.f, p2 = 0.f, p3 = 0.f;
#pragma unroll
    for (int kt = 0; kt < 2; ++kt) {
#pragma unroll
      for (int r = 0; r < 16; r += 4) {
        float e0 = __builtin_amdgcn_exp2f(fmaf(sacc[kt][r + 0], K1, nm));
        float e1 = __builtin_amdgcn_exp2f(fmaf(sacc[kt][r + 1], K1, nm));
        float e2 = __builtin_amdgcn_exp2f(fmaf(sacc[kt][r + 2], K1, nm));
        float e3 = __builtin_amdgcn_exp2f(fmaf(sacc[kt][r + 3], K1, nm));
        sacc[kt][r + 0] = e0; p0 += e0;
        sacc[kt][r + 1] = e1; p1 += e1;
        sacc[kt][r + 2] = e2; p2 += e2;
        sacc[kt][r + 3] = e3; p3 += e3;
      }
    }
    lst += (p0 + p1) + (p2 + p3);  // half-lane-partial l (reduced at epilogue)

    // ---- O^T += V^T * P^T (32x32x16), 4 k-steps of 16 ----
#pragma unroll
    for (int st = 0; st < 4; ++st) {
      const int kt = st >> 1;
      const int R  = 8 * (st & 1);
      // assemble B-frag: lane (q=ml,hi) needs k = st*16 + hi*8 + (0..7)
      // proven shfl_xor exchange (round-0 form)
      unsigned pA0 = pkh(sacc[kt][R + 0], sacc[kt][R + 1]);
      unsigned pA1 = pkh(sacc[kt][R + 2], sacc[kt][R + 3]);
      unsigned pB0 = pkh(sacc[kt][R + 4], sacc[kt][R + 5]);
      unsigned pB1 = pkh(sacc[kt][R + 6], sacc[kt][R + 7]);
      unsigned s0 = hib ? pA0 : pB0;
      unsigned s1 = hib ? pA1 : pB1;
      unsigned r0 = (unsigned)__shfl_xor((int)s0, 32, 64);
      unsigned r1 = (unsigned)__shfl_xor((int)s1, 32, 64);
      int4 bf;
      bf.x = (int)(hib ? r0 : pA0);
      bf.y = (int)(hib ? r1 : pA1);
      bf.z = (int)(hib ? pB0 : r0);
      bf.w = (int)(hib ? pB1 : r1);
      f16x8 pfrag = __builtin_bit_cast(f16x8, bf);
      __builtin_amdgcn_s_setprio(1);
#pragma unroll
      for (int dt = 0; dt < 4; ++dt) {
        int d = dt * 32 + ml;
        int pos = (2 * st + hi) ^ (((d >> 3) ^ d) & 7);
        f16x8 vf = *(const f16x8*)(vt_lds + d * 64 + pos * 8);
        oacc[dt] = __builtin_amdgcn_mfma_f32_32x32x16_f16(
            vf, pfrag, oacc[dt], 0, 0, 0);
      }
      __builtin_amdgcn_s_setprio(0);
    }
  }

  // ---- epilogue: finish l across half-waves, normalize, float4 stores ----
  float lf = lst + __shfl_xor(lst, 32, 64);
  float linv = 1.0f / lf;
#pragma unroll
  for (int dt = 0; dt < 4; ++dt) {
#pragma unroll
    for (int t = 0; t < 4; ++t) {
      f32x4 ov;
      ov[0] = oacc[dt][4 * t + 0] * linv;
      ov[1] = oacc[dt][4 * t + 1] * linv;
      ov[2] = oacc[dt][4 * t + 2] * linv;
      ov[3] = oacc[dt][4 * t + 3] * linv;
      *(f32x4*)(Ow + ml * HD + dt * 32 + 8 * t + 4 * hi) = ov;
    }
  }
}

extern "C" void kernel_launch(void* const* d_in, const int* in_sizes, int n_in,
                              void* d_out, int out_size, void* d_ws, size_t ws_size,
                              hipStream_t stream) {
  const float* q = (const float*)d_in[0];
  const float* k = (const float*)d_in[1];
  const float* v = (const float*)d_in[2];
  float* o = (float*)d_out;
  fa_gqa_kernel<<<dim3(1024), dim3(256), 0, stream>>>(q, k, v, o);
}

// Round 3
// 546.930 us; speedup vs baseline: 2.0426x; 2.0426x over previous
//
#include <hip/hip_runtime.h>

#define SEQ   2048
#define HD    128
#define BN    64
#define NITER (SEQ / BN)

typedef __fp16 f16x8  __attribute__((ext_vector_type(8)));
typedef float  f32x4  __attribute__((ext_vector_type(4)));
typedef float  f32x16 __attribute__((ext_vector_type(16)));

// pack two fp32 -> one uint of two f16 (RTZ)
__device__ __forceinline__ unsigned pkh(float a, float b) {
  auto h = __builtin_amdgcn_cvt_pkrtz(a, b);
  return __builtin_bit_cast(unsigned, h);
}

__global__ __launch_bounds__(256, 2)
void fa_gqa_kernel(const float* __restrict__ Q,
                   const float* __restrict__ K,
                   const float* __restrict__ V,
                   float* __restrict__ O)
{
  // Double-buffered tiles (one barrier per iteration):
  // K tile [64 k][128 d] f16; 16B chunk j at position j ^ (row&15)
  __shared__ unsigned short kt_lds[2][64 * HD];
  // V^T tile [128 d][64 k] f16; 16B chunk c8 (8 k) at pos c8 ^ (((d>>3)^d)&7)
  __shared__ unsigned short vt_lds[2][HD * 64];

  const int tid  = threadIdx.x;
  const int lane = tid & 63;
  const int w    = tid >> 6;
  const int ml   = lane & 31;   // 32x32 MFMA row/col lane index
  const int hi   = lane >> 5;   // half-wave select
  const bool hib = (hi != 0);

  // XCD-clustered virtual block mapping (K/V L2 locality)
  const int F     = blockIdx.x;        // 0..1023
  const int xcd   = F & 7;
  const int s     = F >> 3;
  const int bh    = xcd * 8 + (s >> 4);
  const int qtile = s & 15;

  const int b = bh >> 5;
  const int h = bh & 31;
  const long qrow0 = (long)bh * SEQ + qtile * 128 + w * 32;
  const float* Qw = Q + qrow0 * HD;
  float*       Ow = O + qrow0 * HD;
  const long kvoff = (long)(b * 8 + (h >> 2)) * SEQ * HD;
  const float* Kb = K + kvoff;
  const float* Vb = V + kvoff;

  // Q fragments (B-operand of 32x32x16: lane holds Q[q=w*32+ml][d=dc*16+hi*8+j])
  f16x8 qf[8];
#pragma unroll
  for (int dc = 0; dc < 8; ++dc) {
    const float4* qp = (const float4*)(Qw + ml * HD + dc * 16 + hi * 8);
    float4 a = qp[0], bq = qp[1];
    int4 t;
    t.x = (int)pkh(a.x, a.y);
    t.y = (int)pkh(a.z, a.w);
    t.z = (int)pkh(bq.x, bq.y);
    t.w = (int)pkh(bq.z, bq.w);
    qf[dc] = __builtin_bit_cast(f16x8, t);
  }

  // O^T accumulators: 4 d-tiles of 32x32; lane holds O[q=ml][d=dt*32+(r&3)+8(r>>2)+4hi]
  f32x16 oacc[4];
#pragma unroll
  for (int dt = 0; dt < 4; ++dt)
    oacc[dt] = (f32x16)(0.f);

  float mst = -1e30f;
  float lst = 0.f;

  const float K1 = 0.08838834764831845f * 1.4426950408889634f; // scale*log2(e)

  // staging roles
  const int krow = tid >> 2;      // K: 0..63
  const int kq4  = tid & 3;       // K: 32-float quarter of the row
  const int kq   = tid >> 4;      // V: k-quad 0..15 (rows 4kq..4kq+3)
  const int dc8  = tid & 15;      // V: 8-float d chunk

  const float* kp0 = Kb + (long)krow * HD + kq4 * 32;
  const float* vp0 = Vb + (long)(4 * kq) * HD + dc8 * 8;

  // raw fp32 staging registers (live across compute: that's the pipeline)
  float4 kraw[8];
  float4 vraw[4][2];

  // ---- prologue: load + cvt + store tile 0 into buf 0 ----
#pragma unroll
  for (int i = 0; i < 8; ++i)
    kraw[i] = ((const float4*)kp0)[i];
#pragma unroll
  for (int r = 0; r < 4; ++r) {
    vraw[r][0] = ((const float4*)(vp0 + r * HD))[0];
    vraw[r][1] = ((const float4*)(vp0 + r * HD))[1];
  }
  {
    int4 ks[4];
#pragma unroll
    for (int jj = 0; jj < 4; ++jj) {
      float4 e = kraw[2 * jj], o = kraw[2 * jj + 1];
      ks[jj].x = (int)pkh(e.x, e.y);
      ks[jj].y = (int)pkh(e.z, e.w);
      ks[jj].z = (int)pkh(o.x, o.y);
      ks[jj].w = (int)pkh(o.z, o.w);
      int j = kq4 * 4 + jj;
      int pos = j ^ (krow & 15);
      *(int4*)(kt_lds[0] + krow * HD + pos * 8) = ks[jj];
    }
#pragma unroll
    for (int jd = 0; jd < 8; ++jd) {
      const int hsel = jd >> 2, e = jd & 3;
      uint2 v2;
      v2.x = pkh(((const float*)&vraw[0][hsel])[e], ((const float*)&vraw[1][hsel])[e]);
      v2.y = pkh(((const float*)&vraw[2][hsel])[e], ((const float*)&vraw[3][hsel])[e]);
      int d = dc8 * 8 + jd;
      int sw3 = ((d >> 3) ^ d) & 7;
      int pos = (kq >> 1) ^ sw3;
      *(uint2*)(vt_lds[0] + d * 64 + pos * 8 + (kq & 1) * 4) = v2;
    }
  }

  for (int it = 0; it < NITER; ++it) {
    const int cur = it & 1;
    __syncthreads();  // buf[cur] staged & visible; buf[cur^1] free

    // ---- issue NEXT tile's raw global loads (no wait; hidden under compute) ----
    const bool more = (it + 1 < NITER);
    if (more) {
      const float* kp = kp0 + (long)(it + 1) * BN * HD;
#pragma unroll
      for (int i = 0; i < 8; ++i)
        kraw[i] = ((const float4*)kp)[i];
      const float* vp = vp0 + (long)(it + 1) * BN * HD;
#pragma unroll
      for (int r = 0; r < 4; ++r) {
        vraw[r][0] = ((const float4*)(vp + r * HD))[0];
        vraw[r][1] = ((const float4*)(vp + r * HD))[1];
      }
    }

    // ---- S^T = K * Q^T (32x32x16): lane holds S[q=ml][k=kt*32+(r&3)+8(r>>2)+4hi] ----
    f32x16 sacc[2];
    sacc[0] = (f32x16)(0.f);
    sacc[1] = (f32x16)(0.f);

    __builtin_amdgcn_s_setprio(1);
#pragma unroll
    for (int dc = 0; dc < 8; ++dc) {
#pragma unroll
      for (int kt = 0; kt < 2; ++kt) {
        int row = kt * 32 + ml;
        int pos = (2 * dc + hi) ^ (row & 15);
        f16x8 af = *(const f16x8*)(kt_lds[cur] + row * HD + pos * 8);
        sacc[kt] = __builtin_amdgcn_mfma_f32_32x32x16_f16(
            af, qf[dc], sacc[kt], 0, 0, 0);
      }
    }
    __builtin_amdgcn_s_setprio(0);

    // ---- online softmax: one q-column per lane ----
    // 4-way parallel max chains (~4x less dep depth than serial)
    float x0 = fmaxf(sacc[0][0], sacc[1][0]);
    float x1 = fmaxf(sacc[0][1], sacc[1][1]);
    float x2 = fmaxf(sacc[0][2], sacc[1][2]);
    float x3 = fmaxf(sacc[0][3], sacc[1][3]);
#pragma unroll
    for (int r = 4; r < 16; r += 4) {
      x0 = fmaxf(x0, fmaxf(sacc[0][r + 0], sacc[1][r + 0]));
      x1 = fmaxf(x1, fmaxf(sacc[0][r + 1], sacc[1][r + 1]));
      x2 = fmaxf(x2, fmaxf(sacc[0][r + 2], sacc[1][r + 2]));
      x3 = fmaxf(x3, fmaxf(sacc[0][r + 3], sacc[1][r + 3]));
    }
    float mx = fmaxf(fmaxf(x0, x1), fmaxf(x2, x3));
    mx = fmaxf(mx, __shfl_xor(mx, 32, 64));  // proven cross-half reduce

    // defer-max: skip rescale when running max unchanged (alpha would be exactly 1)
    if (__any(mx > mst)) {
      float mnew = fmaxf(mst, mx);
      float alpha = __builtin_amdgcn_exp2f(K1 * (mst - mnew));
      mst = mnew;
      lst *= alpha;
#pragma unroll
      for (int dt = 0; dt < 4; ++dt)
        oacc[dt] *= alpha;
    }

    const float nm = -K1 * mst;
    float p0 = 0.f, p1 = 0.f, p2 = 0.f, p3 = 0.f;
#pragma unroll
    for (int kt = 0; kt < 2; ++kt) {
#pragma unroll
      for (int r = 0; r < 16; r += 4) {
        float e0 = __builtin_amdgcn_exp2f(fmaf(sacc[kt][r + 0], K1, nm));
        float e1 = __builtin_amdgcn_exp2f(fmaf(sacc[kt][r + 1], K1, nm));
        float e2 = __builtin_amdgcn_exp2f(fmaf(sacc[kt][r + 2], K1, nm));
        float e3 = __builtin_amdgcn_exp2f(fmaf(sacc[kt][r + 3], K1, nm));
        sacc[kt][r + 0] = e0; p0 += e0;
        sacc[kt][r + 1] = e1; p1 += e1;
        sacc[kt][r + 2] = e2; p2 += e2;
        sacc[kt][r + 3] = e3; p3 += e3;
      }
    }
    lst += (p0 + p1) + (p2 + p3);  // half-lane-partial l (reduced at epilogue)

    // ---- O^T += V^T * P^T (32x32x16), 4 k-steps of 16 ----
#pragma unroll
    for (int st = 0; st < 4; ++st) {
      const int kt = st >> 1;
      const int R  = 8 * (st & 1);
      // assemble B-frag: lane (q=ml,hi) needs k = st*16 + hi*8 + (0..7)
      unsigned pA0 = pkh(sacc[kt][R + 0], sacc[kt][R + 1]);
      unsigned pA1 = pkh(sacc[kt][R + 2], sacc[kt][R + 3]);
      unsigned pB0 = pkh(sacc[kt][R + 4], sacc[kt][R + 5]);
      unsigned pB1 = pkh(sacc[kt][R + 6], sacc[kt][R + 7]);
      unsigned s0 = hib ? pA0 : pB0;
      unsigned s1 = hib ? pA1 : pB1;
      unsigned r0 = (unsigned)__shfl_xor((int)s0, 32, 64);
      unsigned r1 = (unsigned)__shfl_xor((int)s1, 32, 64);
      int4 bf;
      bf.x = (int)(hib ? r0 : pA0);
      bf.y = (int)(hib ? r1 : pA1);
      bf.z = (int)(hib ? pB0 : r0);
      bf.w = (int)(hib ? pB1 : r1);
      f16x8 pfrag = __builtin_bit_cast(f16x8, bf);
      __builtin_amdgcn_s_setprio(1);
#pragma unroll
      for (int dt = 0; dt < 4; ++dt) {
        int d = dt * 32 + ml;
        int pos = (2 * st + hi) ^ (((d >> 3) ^ d) & 7);
        f16x8 vf = *(const f16x8*)(vt_lds[cur] + d * 64 + pos * 8);
        oacc[dt] = __builtin_amdgcn_mfma_f32_32x32x16_f16(
            vf, pfrag, oacc[dt], 0, 0, 0);
      }
      __builtin_amdgcn_s_setprio(0);
    }

    // ---- tail: cvt raw regs -> f16, store into buf[cur^1] (vmcnt wait lands here) ----
    if (more) {
      const int nxt = cur ^ 1;
#pragma unroll
      for (int jj = 0; jj < 4; ++jj) {
        float4 e = kraw[2 * jj], o = kraw[2 * jj + 1];
        int4 ksj;
        ksj.x = (int)pkh(e.x, e.y);
        ksj.y = (int)pkh(e.z, e.w);
        ksj.z = (int)pkh(o.x, o.y);
        ksj.w = (int)pkh(o.z, o.w);
        int j = kq4 * 4 + jj;
        int pos = j ^ (krow & 15);
        *(int4*)(kt_lds[nxt] + krow * HD + pos * 8) = ksj;
      }
#pragma unroll
      for (int jd = 0; jd < 8; ++jd) {
        const int hsel = jd >> 2, e = jd & 3;
        uint2 v2;
        v2.x = pkh(((const float*)&vraw[0][hsel])[e], ((const float*)&vraw[1][hsel])[e]);
        v2.y = pkh(((const float*)&vraw[2][hsel])[e], ((const float*)&vraw[3][hsel])[e]);
        int d = dc8 * 8 + jd;
        int sw3 = ((d >> 3) ^ d) & 7;
        int pos = (kq >> 1) ^ sw3;
        *(uint2*)(vt_lds[nxt] + d * 64 + pos * 8 + (kq & 1) * 4) = v2;
      }
    }
  }

  // ---- epilogue: finish l across half-waves, normalize, float4 stores ----
  float lf = lst + __shfl_xor(lst, 32, 64);
  float linv = 1.0f / lf;
#pragma unroll
  for (int dt = 0; dt < 4; ++dt) {
#pragma unroll
    for (int t = 0; t < 4; ++t) {
      f32x4 ov;
      ov[0] = oacc[dt][4 * t + 0] * linv;
      ov[1] = oacc[dt][4 * t + 1] * linv;
      ov[2] = oacc[dt][4 * t + 2] * linv;
      ov[3] = oacc[dt][4 * t + 3] * linv;
      *(f32x4*)(Ow + ml * HD + dt * 32 + 8 * t + 4 * hi) = ov;
    }
  }
}

extern "C" void kernel_launch(void* const* d_in, const int* in_sizes, int n_in,
                              void* d_out, int out_size, void* d_ws, size_t ws_size,
                              hipStream_t stream) {
  const float* q = (const float*)d_in[0];
  const float* k = (const float*)d_in[1];
  const float* v = (const float*)d_in[2];
  float* o = (float*)d_out;
  fa_gqa_kernel<<<dim3(1024), dim3(256), 0, stream>>>(q, k, v, o);
}

// Round 4
// 384.287 us; speedup vs baseline: 2.9071x; 1.4232x over previous
//
#include <hip/hip_runtime.h>

#define SEQ   2048
#define HD    128
#define BN    64
#define NITER (SEQ / BN)

typedef __fp16 f16x8  __attribute__((ext_vector_type(8)));
typedef float  f32x4  __attribute__((ext_vector_type(4)));
typedef float  f32x16 __attribute__((ext_vector_type(16)));

// pack two fp32 -> one uint of two f16 (RTZ)
__device__ __forceinline__ unsigned pkh(float a, float b) {
  auto h = __builtin_amdgcn_cvt_pkrtz(a, b);
  return __builtin_bit_cast(unsigned, h);
}

// 512 threads (8 waves) / block, 1 block per CU, VGPR cap 256 (2 waves/SIMD).
__global__ __launch_bounds__(512, 2)
void fa_gqa_kernel(const float* __restrict__ Q,
                   const float* __restrict__ K,
                   const float* __restrict__ V,
                   float* __restrict__ O)
{
  // Double-buffered tiles (one barrier per iteration):
  // K tile [64 k][128 d] f16; 16B chunk j at position j ^ (row&15)
  __shared__ unsigned short kt_lds[2][64 * HD];
  // V^T tile [128 d][64 k] f16; 16B chunk c8 (8 k) at pos c8 ^ (((d>>3)^d)&7)
  __shared__ unsigned short vt_lds[2][HD * 64];

  const int tid  = threadIdx.x;
  const int lane = tid & 63;
  const int w    = tid >> 6;    // 0..7 waves
  const int ml   = lane & 31;   // 32x32 MFMA row/col lane index
  const int hi   = lane >> 5;   // half-wave select
  const bool hib = (hi != 0);

  // grid: 512 blocks = 64 bh x 8 qtiles; XCD-clustered so each XCD sees
  // 8 bh = 2 KV heads = 4 MB of K+V (one L2's worth)
  const int F     = blockIdx.x;        // 0..511
  const int xcd   = F & 7;
  const int s     = F >> 3;            // 0..63
  const int bh    = xcd * 8 + (s >> 3);
  const int qtile = s & 7;

  const int b = bh >> 5;
  const int h = bh & 31;
  const long qrow0 = (long)bh * SEQ + qtile * 256 + w * 32;
  const float* Qw = Q + qrow0 * HD;
  float*       Ow = O + qrow0 * HD;
  const long kvoff = (long)(b * 8 + (h >> 2)) * SEQ * HD;
  const float* Kb = K + kvoff;
  const float* Vb = V + kvoff;

  // Q fragments (B-operand of 32x32x16: lane holds Q[q=w*32+ml][d=dc*16+hi*8+j])
  f16x8 qf[8];
#pragma unroll
  for (int dc = 0; dc < 8; ++dc) {
    const float4* qp = (const float4*)(Qw + ml * HD + dc * 16 + hi * 8);
    float4 a = qp[0], bq = qp[1];
    int4 t;
    t.x = (int)pkh(a.x, a.y);
    t.y = (int)pkh(a.z, a.w);
    t.z = (int)pkh(bq.x, bq.y);
    t.w = (int)pkh(bq.z, bq.w);
    qf[dc] = __builtin_bit_cast(f16x8, t);
  }

  // O^T accumulators: 4 d-tiles of 32x32; lane holds O[q=ml][d=dt*32+(r&3)+8(r>>2)+4hi]
  f32x16 oacc[4];
#pragma unroll
  for (int dt = 0; dt < 4; ++dt)
    oacc[dt] = (f32x16)(0.f);

  float mst = -1e30f;
  float lst = 0.f;

  const float K1 = 0.08838834764831845f * 1.4426950408889634f; // scale*log2(e)

  // staging roles (512 threads; 16 K floats + 16 V floats per thread)
  const int krow = tid >> 3;      // K: row 0..63 (8 threads/row)
  const int kseg = tid & 7;       // K: 16-float segment of the row
  const int kq   = tid >> 5;      // V: k-quad 0..15 (rows 4kq..4kq+3)
  const int dc4  = tid & 31;      // V: 4-float d chunk (d = dc4*4..+3)

  const float* kp0 = Kb + (long)krow * HD + kseg * 16;
  const float* vp0 = Vb + (long)(4 * kq) * HD + dc4 * 4;

  // raw fp32 prefetch registers (live across compute: that's the pipeline)
  float4 kraw[4];
  float4 vraw[4];

  // ---- prologue: load + cvt + store tile 0 into buf 0 ----
#pragma unroll
  for (int i = 0; i < 4; ++i)
    kraw[i] = ((const float4*)kp0)[i];
#pragma unroll
  for (int r = 0; r < 4; ++r)
    vraw[r] = *(const float4*)(vp0 + r * HD);
  {
#pragma unroll
    for (int jj = 0; jj < 2; ++jj) {
      float4 e = kraw[2 * jj], o = kraw[2 * jj + 1];
      int4 ksj;
      ksj.x = (int)pkh(e.x, e.y);
      ksj.y = (int)pkh(e.z, e.w);
      ksj.z = (int)pkh(o.x, o.y);
      ksj.w = (int)pkh(o.z, o.w);
      int j = kseg * 2 + jj;
      int pos = j ^ (krow & 15);
      *(int4*)(kt_lds[0] + krow * HD + pos * 8) = ksj;
    }
#pragma unroll
    for (int jd = 0; jd < 4; ++jd) {
      uint2 v2;
      v2.x = pkh(((const float*)&vraw[0])[jd], ((const float*)&vraw[1])[jd]);
      v2.y = pkh(((const float*)&vraw[2])[jd], ((const float*)&vraw[3])[jd]);
      int d = dc4 * 4 + jd;
      int sw3 = ((d >> 3) ^ d) & 7;
      int pos = (kq >> 1) ^ sw3;
      *(uint2*)(vt_lds[0] + d * 64 + pos * 8 + (kq & 1) * 4) = v2;
    }
  }

  for (int it = 0; it < NITER; ++it) {
    const int cur = it & 1;
    __syncthreads();  // buf[cur] staged & visible; buf[cur^1] free

    // ---- issue NEXT tile's raw global loads (no wait; hidden under compute) ----
    const bool more = (it + 1 < NITER);
    if (more) {
      const float* kp = kp0 + (long)(it + 1) * BN * HD;
#pragma unroll
      for (int i = 0; i < 4; ++i)
        kraw[i] = ((const float4*)kp)[i];
      const float* vp = vp0 + (long)(it + 1) * BN * HD;
#pragma unroll
      for (int r = 0; r < 4; ++r)
        vraw[r] = *(const float4*)(vp + r * HD);
    }

    // ---- S^T = K * Q^T (32x32x16): lane holds S[q=ml][k=kt*32+(r&3)+8(r>>2)+4hi] ----
    f32x16 sacc[2];
    sacc[0] = (f32x16)(0.f);
    sacc[1] = (f32x16)(0.f);

    __builtin_amdgcn_s_setprio(1);
#pragma unroll
    for (int dc = 0; dc < 8; ++dc) {
#pragma unroll
      for (int kt = 0; kt < 2; ++kt) {
        int row = kt * 32 + ml;
        int pos = (2 * dc + hi) ^ (row & 15);
        f16x8 af = *(const f16x8*)(kt_lds[cur] + row * HD + pos * 8);
        sacc[kt] = __builtin_amdgcn_mfma_f32_32x32x16_f16(
            af, qf[dc], sacc[kt], 0, 0, 0);
      }
    }
    __builtin_amdgcn_s_setprio(0);

    // ---- online softmax: one q-column per lane ----
    // 4-way parallel max chains (~4x less dep depth than serial)
    float x0 = fmaxf(sacc[0][0], sacc[1][0]);
    float x1 = fmaxf(sacc[0][1], sacc[1][1]);
    float x2 = fmaxf(sacc[0][2], sacc[1][2]);
    float x3 = fmaxf(sacc[0][3], sacc[1][3]);
#pragma unroll
    for (int r = 4; r < 16; r += 4) {
      x0 = fmaxf(x0, fmaxf(sacc[0][r + 0], sacc[1][r + 0]));
      x1 = fmaxf(x1, fmaxf(sacc[0][r + 1], sacc[1][r + 1]));
      x2 = fmaxf(x2, fmaxf(sacc[0][r + 2], sacc[1][r + 2]));
      x3 = fmaxf(x3, fmaxf(sacc[0][r + 3], sacc[1][r + 3]));
    }
    float mx = fmaxf(fmaxf(x0, x1), fmaxf(x2, x3));
    mx = fmaxf(mx, __shfl_xor(mx, 32, 64));  // proven cross-half reduce

    // defer-max: skip rescale when running max unchanged (alpha would be exactly 1)
    if (__any(mx > mst)) {
      float mnew = fmaxf(mst, mx);
      float alpha = __builtin_amdgcn_exp2f(K1 * (mst - mnew));
      mst = mnew;
      lst *= alpha;
#pragma unroll
      for (int dt = 0; dt < 4; ++dt)
        oacc[dt] *= alpha;
    }

    const float nm = -K1 * mst;
    float p0 = 0.f, p1 = 0.f, p2 = 0.f, p3 = 0.f;
#pragma unroll
    for (int kt = 0; kt < 2; ++kt) {
#pragma unroll
      for (int r = 0; r < 16; r += 4) {
        float e0 = __builtin_amdgcn_exp2f(fmaf(sacc[kt][r + 0], K1, nm));
        float e1 = __builtin_amdgcn_exp2f(fmaf(sacc[kt][r + 1], K1, nm));
        float e2 = __builtin_amdgcn_exp2f(fmaf(sacc[kt][r + 2], K1, nm));
        float e3 = __builtin_amdgcn_exp2f(fmaf(sacc[kt][r + 3], K1, nm));
        sacc[kt][r + 0] = e0; p0 += e0;
        sacc[kt][r + 1] = e1; p1 += e1;
        sacc[kt][r + 2] = e2; p2 += e2;
        sacc[kt][r + 3] = e3; p3 += e3;
      }
    }
    lst += (p0 + p1) + (p2 + p3);  // half-lane-partial l (reduced at epilogue)

    // ---- O^T += V^T * P^T (32x32x16), 4 k-steps of 16 ----
#pragma unroll
    for (int st = 0; st < 4; ++st) {
      const int kt = st >> 1;
      const int R  = 8 * (st & 1);
      // assemble B-frag: lane (q=ml,hi) needs k = st*16 + hi*8 + (0..7)
      unsigned pA0 = pkh(sacc[kt][R + 0], sacc[kt][R + 1]);
      unsigned pA1 = pkh(sacc[kt][R + 2], sacc[kt][R + 3]);
      unsigned pB0 = pkh(sacc[kt][R + 4], sacc[kt][R + 5]);
      unsigned pB1 = pkh(sacc[kt][R + 6], sacc[kt][R + 7]);
      unsigned s0 = hib ? pA0 : pB0;
      unsigned s1 = hib ? pA1 : pB1;
      unsigned r0 = (unsigned)__shfl_xor((int)s0, 32, 64);
      unsigned r1 = (unsigned)__shfl_xor((int)s1, 32, 64);
      int4 bf;
      bf.x = (int)(hib ? r0 : pA0);
      bf.y = (int)(hib ? r1 : pA1);
      bf.z = (int)(hib ? pB0 : r0);
      bf.w = (int)(hib ? pB1 : r1);
      f16x8 pfrag = __builtin_bit_cast(f16x8, bf);
      __builtin_amdgcn_s_setprio(1);
#pragma unroll
      for (int dt = 0; dt < 4; ++dt) {
        int d = dt * 32 + ml;
        int pos = (2 * st + hi) ^ (((d >> 3) ^ d) & 7);
        f16x8 vf = *(const f16x8*)(vt_lds[cur] + d * 64 + pos * 8);
        oacc[dt] = __builtin_amdgcn_mfma_f32_32x32x16_f16(
            vf, pfrag, oacc[dt], 0, 0, 0);
      }
      __builtin_amdgcn_s_setprio(0);
    }

    // ---- tail: cvt raw regs -> f16, store into buf[cur^1] (vmcnt wait lands here) ----
    if (more) {
      const int nxt = cur ^ 1;
#pragma unroll
      for (int jj = 0; jj < 2; ++jj) {
        float4 e = kraw[2 * jj], o = kraw[2 * jj + 1];
        int4 ksj;
        ksj.x = (int)pkh(e.x, e.y);
        ksj.y = (int)pkh(e.z, e.w);
        ksj.z = (int)pkh(o.x, o.y);
        ksj.w = (int)pkh(o.z, o.w);
        int j = kseg * 2 + jj;
        int pos = j ^ (krow & 15);
        *(int4*)(kt_lds[nxt] + krow * HD + pos * 8) = ksj;
      }
#pragma unroll
      for (int jd = 0; jd < 4; ++jd) {
        uint2 v2;
        v2.x = pkh(((const float*)&vraw[0])[jd], ((const float*)&vraw[1])[jd]);
        v2.y = pkh(((const float*)&vraw[2])[jd], ((const float*)&vraw[3])[jd]);
        int d = dc4 * 4 + jd;
        int sw3 = ((d >> 3) ^ d) & 7;
        int pos = (kq >> 1) ^ sw3;
        *(uint2*)(vt_lds[nxt] + d * 64 + pos * 8 + (kq & 1) * 4) = v2;
      }
    }
  }

  // ---- epilogue: finish l across half-waves, normalize, float4 stores ----
  float lf = lst + __shfl_xor(lst, 32, 64);
  float linv = 1.0f / lf;
#pragma unroll
  for (int dt = 0; dt < 4; ++dt) {
#pragma unroll
    for (int t = 0; t < 4; ++t) {
      f32x4 ov;
      ov[0] = oacc[dt][4 * t + 0] * linv;
      ov[1] = oacc[dt][4 * t + 1] * linv;
      ov[2] = oacc[dt][4 * t + 2] * linv;
      ov[3] = oacc[dt][4 * t + 3] * linv;
      *(f32x4*)(Ow + ml * HD + dt * 32 + 8 * t + 4 * hi) = ov;
    }
  }
}

extern "C" void kernel_launch(void* const* d_in, const int* in_sizes, int n_in,
                              void* d_out, int out_size, void* d_ws, size_t ws_size,
                              hipStream_t stream) {
  const float* q = (const float*)d_in[0];
  const float* k = (const float*)d_in[1];
  const float* v = (const float*)d_in[2];
  float* o = (float*)d_out;
  fa_gqa_kernel<<<dim3(512), dim3(512), 0, stream>>>(q, k, v, o);
}

// Round 5
// 331.122 us; speedup vs baseline: 3.3739x; 1.1606x over previous
//
#include <hip/hip_runtime.h>

#define SEQ   2048
#define HD    128
#define BN    64
#define NITER (SEQ / BN)

typedef __fp16 f16x8  __attribute__((ext_vector_type(8)));
typedef float  f32x4  __attribute__((ext_vector_type(4)));
typedef float  f32x16 __attribute__((ext_vector_type(16)));

// pack two fp32 -> one uint of two f16 (RTZ)
__device__ __forceinline__ unsigned pkh(float a, float b) {
  auto h = __builtin_amdgcn_cvt_pkrtz(a, b);
  return __builtin_bit_cast(unsigned, h);
}

// R0-proven structure: 256 thr, (256,2), single-buffered LDS, 2 barriers/iter.
// Staging registers time-share with sacc (the register-optimal layout here;
// all prefetch-across-compute variants spilled: R2/R3/R4).
__global__ __launch_bounds__(256, 2)
void fa_gqa_kernel(const float* __restrict__ Q,
                   const float* __restrict__ K,
                   const float* __restrict__ V,
                   float* __restrict__ O)
{
  // K tile [64 k][128 d] f16; 16B chunk j at position j ^ (row&15)
  __shared__ unsigned short kt_lds[64 * HD];
  // V^T tile [128 d][64 k] f16; 16B chunk c8 (8 k) at pos c8 ^ (((d>>3)^d)&7)
  __shared__ unsigned short vt_lds[HD * 64];

  const int tid  = threadIdx.x;
  const int lane = tid & 63;
  const int w    = tid >> 6;
  const int ml   = lane & 31;   // 32x32 MFMA row/col lane index
  const int hi   = lane >> 5;   // half-wave select
  const bool hib = (hi != 0);

  // XCD-clustered virtual block mapping (K/V L2 locality)
  const int F     = blockIdx.x;        // 0..1023
  const int xcd   = F & 7;
  const int s     = F >> 3;
  const int bh    = xcd * 8 + (s >> 4);
  const int qtile = s & 15;

  const int b = bh >> 5;
  const int h = bh & 31;
  const long qrow0 = (long)bh * SEQ + qtile * 128 + w * 32;
  const float* Qw = Q + qrow0 * HD;
  float*       Ow = O + qrow0 * HD;
  const long kvoff = (long)(b * 8 + (h >> 2)) * SEQ * HD;
  const float* Kb = K + kvoff;
  const float* Vb = V + kvoff;

  // Q fragments (B-operand of 32x32x16: lane holds Q[q=w*32+ml][d=dc*16+hi*8+j])
  f16x8 qf[8];
#pragma unroll
  for (int dc = 0; dc < 8; ++dc) {
    const float4* qp = (const float4*)(Qw + ml * HD + dc * 16 + hi * 8);
    float4 a = qp[0], bq = qp[1];
    int4 t;
    t.x = (int)pkh(a.x, a.y);
    t.y = (int)pkh(a.z, a.w);
    t.z = (int)pkh(bq.x, bq.y);
    t.w = (int)pkh(bq.z, bq.w);
    qf[dc] = __builtin_bit_cast(f16x8, t);
  }

  // O^T accumulators: 4 d-tiles of 32x32; lane holds O[q=ml][d=dt*32+(r&3)+8(r>>2)+4hi]
  f32x16 oacc[4];
#pragma unroll
  for (int dt = 0; dt < 4; ++dt)
    oacc[dt] = (f32x16)(0.f);

  float mst = -1e30f;
  float lst = 0.f;

  const float K1 = 0.08838834764831845f * 1.4426950408889634f; // scale*log2(e)

  // staging roles
  const int krow = tid >> 2;      // K: 0..63
  const int kq4  = tid & 3;       // K: 32-float quarter of the row
  const int kq   = tid >> 4;      // V: k-quad 0..15 (rows 4kq..4kq+3)
  const int dc8  = tid & 15;      // V: 8-float d chunk

  for (int it = 0; it < NITER; ++it) {
    const int k0 = it * BN;

    // ---- global loads + cvt to f16 (pre-barrier) ----
    const float* kp = Kb + (long)(k0 + krow) * HD + kq4 * 32;
    int4 ks[4];
#pragma unroll
    for (int jj = 0; jj < 4; ++jj) {
      float4 e = ((const float4*)kp)[2 * jj];
      float4 o = ((const float4*)kp)[2 * jj + 1];
      ks[jj].x = (int)pkh(e.x, e.y);
      ks[jj].y = (int)pkh(e.z, e.w);
      ks[jj].z = (int)pkh(o.x, o.y);
      ks[jj].w = (int)pkh(o.z, o.w);
    }

    const float* vp = Vb + (long)(k0 + 4 * kq) * HD + dc8 * 8;
    float4 vr[4][2];
#pragma unroll
    for (int r = 0; r < 4; ++r) {
      vr[r][0] = ((const float4*)(vp + r * HD))[0];
      vr[r][1] = ((const float4*)(vp + r * HD))[1];
    }
    uint2 vs[8];
#pragma unroll
    for (int jd = 0; jd < 8; ++jd) {
      const int hsel = jd >> 2, e = jd & 3;
      float x0 = ((const float*)&vr[0][hsel])[e];
      float x1 = ((const float*)&vr[1][hsel])[e];
      float x2 = ((const float*)&vr[2][hsel])[e];
      float x3 = ((const float*)&vr[3][hsel])[e];
      vs[jd].x = pkh(x0, x1);
      vs[jd].y = pkh(x2, x3);
    }

    __syncthreads();  // (A) all waves done reading prev tiles

    // K staging: 4 swizzled b128 stores
#pragma unroll
    for (int jj = 0; jj < 4; ++jj) {
      int j = kq4 * 4 + jj;
      int pos = j ^ (krow & 15);
      *(int4*)(kt_lds + krow * HD + pos * 8) = ks[jj];
    }
    // V^T staging: 8 swizzled b64 stores; 16B chunk (kq>>1) at pos ^ sw3(d)
#pragma unroll
    for (int jd = 0; jd < 8; ++jd) {
      int d = dc8 * 8 + jd;
      int sw3 = ((d >> 3) ^ d) & 7;
      int pos = (kq >> 1) ^ sw3;
      *(uint2*)(vt_lds + d * 64 + pos * 8 + (kq & 1) * 4) = vs[jd];
    }

    __syncthreads();  // (B) staging visible

    // ---- S^T = K * Q^T (32x32x16): lane holds S[q=ml][k=kt*32+(r&3)+8(r>>2)+4hi] ----
    f32x16 sacc[2];
    sacc[0] = (f32x16)(0.f);
    sacc[1] = (f32x16)(0.f);

    __builtin_amdgcn_s_setprio(1);
#pragma unroll
    for (int dc = 0; dc < 8; ++dc) {
#pragma unroll
      for (int kt = 0; kt < 2; ++kt) {
        int row = kt * 32 + ml;
        int pos = (2 * dc + hi) ^ (row & 15);
        f16x8 af = *(const f16x8*)(kt_lds + row * HD + pos * 8);
        sacc[kt] = __builtin_amdgcn_mfma_f32_32x32x16_f16(
            af, qf[dc], sacc[kt], 0, 0, 0);
      }
    }
    __builtin_amdgcn_s_setprio(0);

    // ---- online softmax: one q-column per lane ----
    // 4-way parallel max chains (~4x less dep depth than serial)
    float x0 = fmaxf(sacc[0][0], sacc[1][0]);
    float x1 = fmaxf(sacc[0][1], sacc[1][1]);
    float x2 = fmaxf(sacc[0][2], sacc[1][2]);
    float x3 = fmaxf(sacc[0][3], sacc[1][3]);
#pragma unroll
    for (int r = 4; r < 16; r += 4) {
      x0 = fmaxf(x0, fmaxf(sacc[0][r + 0], sacc[1][r + 0]));
      x1 = fmaxf(x1, fmaxf(sacc[0][r + 1], sacc[1][r + 1]));
      x2 = fmaxf(x2, fmaxf(sacc[0][r + 2], sacc[1][r + 2]));
      x3 = fmaxf(x3, fmaxf(sacc[0][r + 3], sacc[1][r + 3]));
    }
    float mx = fmaxf(fmaxf(x0, x1), fmaxf(x2, x3));
    mx = fmaxf(mx, __shfl_xor(mx, 32, 64));  // cross-half reduce

    // defer-max: skip rescale when running max unchanged (alpha would be exactly 1)
    if (__any(mx > mst)) {
      float mnew = fmaxf(mst, mx);
      float alpha = __builtin_amdgcn_exp2f(K1 * (mst - mnew));
      mst = mnew;
      lst *= alpha;
#pragma unroll
      for (int dt = 0; dt < 4; ++dt)
        oacc[dt] *= alpha;
    }

    const float nm = -K1 * mst;
    float p0 = 0.f, p1 = 0.f, p2 = 0.f, p3 = 0.f;
#pragma unroll
    for (int kt = 0; kt < 2; ++kt) {
#pragma unroll
      for (int r = 0; r < 16; r += 4) {
        float e0 = __builtin_amdgcn_exp2f(fmaf(sacc[kt][r + 0], K1, nm));
        float e1 = __builtin_amdgcn_exp2f(fmaf(sacc[kt][r + 1], K1, nm));
        float e2 = __builtin_amdgcn_exp2f(fmaf(sacc[kt][r + 2], K1, nm));
        float e3 = __builtin_amdgcn_exp2f(fmaf(sacc[kt][r + 3], K1, nm));
        sacc[kt][r + 0] = e0; p0 += e0;
        sacc[kt][r + 1] = e1; p1 += e1;
        sacc[kt][r + 2] = e2; p2 += e2;
        sacc[kt][r + 3] = e3; p3 += e3;
      }
    }
    lst += (p0 + p1) + (p2 + p3);  // half-lane-partial l (reduced at epilogue)

    // ---- O^T += V^T * P^T (32x32x16), 4 k-steps of 16 ----
#pragma unroll
    for (int st = 0; st < 4; ++st) {
      const int kt = st >> 1;
      const int R  = 8 * (st & 1);
      // assemble B-frag: lane (q=ml,hi) needs k = st*16 + hi*8 + (0..7)
      unsigned pA0 = pkh(sacc[kt][R + 0], sacc[kt][R + 1]);
      unsigned pA1 = pkh(sacc[kt][R + 2], sacc[kt][R + 3]);
      unsigned pB0 = pkh(sacc[kt][R + 4], sacc[kt][R + 5]);
      unsigned pB1 = pkh(sacc[kt][R + 6], sacc[kt][R + 7]);
      unsigned s0 = hib ? pA0 : pB0;
      unsigned s1 = hib ? pA1 : pB1;
      unsigned r0 = (unsigned)__shfl_xor((int)s0, 32, 64);
      unsigned r1 = (unsigned)__shfl_xor((int)s1, 32, 64);
      int4 bf;
      bf.x = (int)(hib ? r0 : pA0);
      bf.y = (int)(hib ? r1 : pA1);
      bf.z = (int)(hib ? pB0 : r0);
      bf.w = (int)(hib ? pB1 : r1);
      f16x8 pfrag = __builtin_bit_cast(f16x8, bf);
      __builtin_amdgcn_s_setprio(1);
#pragma unroll
      for (int dt = 0; dt < 4; ++dt) {
        int d = dt * 32 + ml;
        int pos = (2 * st + hi) ^ (((d >> 3) ^ d) & 7);
        f16x8 vf = *(const f16x8*)(vt_lds + d * 64 + pos * 8);
        oacc[dt] = __builtin_amdgcn_mfma_f32_32x32x16_f16(
            vf, pfrag, oacc[dt], 0, 0, 0);
      }
      __builtin_amdgcn_s_setprio(0);
    }
  }

  // ---- epilogue: finish l across half-waves, normalize, float4 stores ----
  float lf = lst + __shfl_xor(lst, 32, 64);
  float linv = 1.0f / lf;
#pragma unroll
  for (int dt = 0; dt < 4; ++dt) {
#pragma unroll
    for (int t = 0; t < 4; ++t) {
      f32x4 ov;
      ov[0] = oacc[dt][4 * t + 0] * linv;
      ov[1] = oacc[dt][4 * t + 1] * linv;
      ov[2] = oacc[dt][4 * t + 2] * linv;
      ov[3] = oacc[dt][4 * t + 3] * linv;
      *(f32x4*)(Ow + ml * HD + dt * 32 + 8 * t + 4 * hi) = ov;
    }
  }
}

extern "C" void kernel_launch(void* const* d_in, const int* in_sizes, int n_in,
                              void* d_out, int out_size, void* d_ws, size_t ws_size,
                              hipStream_t stream) {
  const float* q = (const float*)d_in[0];
  const float* k = (const float*)d_in[1];
  const float* v = (const float*)d_in[2];
  float* o = (float*)d_out;
  fa_gqa_kernel<<<dim3(1024), dim3(256), 0, stream>>>(q, k, v, o);
}

// Round 6
// 315.023 us; speedup vs baseline: 3.5463x; 1.0511x over previous
//
#include <hip/hip_runtime.h>

#define SEQ   2048
#define HD    128
#define BN    128
#define NITER (SEQ / BN)

typedef __fp16 f16x8  __attribute__((ext_vector_type(8)));
typedef float  f32x4  __attribute__((ext_vector_type(4)));
typedef float  f32x16 __attribute__((ext_vector_type(16)));

// pack two fp32 -> one uint of two f16 (RTZ)
__device__ __forceinline__ unsigned pkh(float a, float b) {
  auto h = __builtin_amdgcn_cvt_pkrtz(a, b);
  return __builtin_bit_cast(unsigned, h);
}

// 512 threads (8 waves), BN=128: one barrier pair + one load-latency exposure
// per 128 k-rows (R0 paid two). Per-thread staging register shapes identical
// to the proven R0 layout (no prefetch-across-compute: R2/R3/R4 all spilled).
// Unified VGPR+AGPR footprint ~220/wave -> 2 waves/SIMD regardless of bounds.
__global__ __launch_bounds__(512, 2)
void fa_gqa_kernel(const float* __restrict__ Q,
                   const float* __restrict__ K,
                   const float* __restrict__ V,
                   float* __restrict__ O)
{
  // K tile [128 k][128 d] f16; 16B chunk j at position j ^ (row&15)
  __shared__ unsigned short kt_lds[BN * HD];
  // V^T tile [128 d][128 k] f16; 16B chunk c8 at pos (c8&8)|((c8&7)^sw3(d))
  __shared__ unsigned short vt_lds[HD * BN];

  const int tid  = threadIdx.x;
  const int lane = tid & 63;
  const int w    = tid >> 6;    // 0..7 waves
  const int ml   = lane & 31;   // 32x32 MFMA row/col lane index
  const int hi   = lane >> 5;   // half-wave select
  const bool hib = (hi != 0);

  // grid: 512 blocks = 64 bh x 8 qtiles; XCD-clustered so each XCD sees
  // 8 bh = 2 KV heads = 4 MB of K+V (one L2's worth)
  const int F     = blockIdx.x;        // 0..511
  const int xcd   = F & 7;
  const int s     = F >> 3;            // 0..63
  const int bh    = xcd * 8 + (s >> 3);
  const int qtile = s & 7;

  const int b = bh >> 5;
  const int h = bh & 31;
  const long qrow0 = (long)bh * SEQ + qtile * 256 + w * 32;
  const float* Qw = Q + qrow0 * HD;
  float*       Ow = O + qrow0 * HD;
  const long kvoff = (long)(b * 8 + (h >> 2)) * SEQ * HD;
  const float* Kb = K + kvoff;
  const float* Vb = V + kvoff;

  // Q fragments (B-operand of 32x32x16: lane holds Q[q=w*32+ml][d=dc*16+hi*8+j])
  f16x8 qf[8];
#pragma unroll
  for (int dc = 0; dc < 8; ++dc) {
    const float4* qp = (const float4*)(Qw + ml * HD + dc * 16 + hi * 8);
    float4 a = qp[0], bq = qp[1];
    int4 t;
    t.x = (int)pkh(a.x, a.y);
    t.y = (int)pkh(a.z, a.w);
    t.z = (int)pkh(bq.x, bq.y);
    t.w = (int)pkh(bq.z, bq.w);
    qf[dc] = __builtin_bit_cast(f16x8, t);
  }

  // O^T accumulators: 4 d-tiles of 32x32; lane holds O[q=ml][d=dt*32+(r&3)+8(r>>2)+4hi]
  f32x16 oacc[4];
#pragma unroll
  for (int dt = 0; dt < 4; ++dt)
    oacc[dt] = (f32x16)(0.f);

  float mst = -1e30f;
  float lst = 0.f;

  const float K1 = 0.08838834764831845f * 1.4426950408889634f; // scale*log2(e)

  // staging roles (512 threads stage 128 rows exactly as 256 threads staged 64)
  const int krow = tid >> 2;      // K: row 0..127 (4 threads/row)
  const int kq4  = tid & 3;       // K: 32-float quarter of the row
  const int kq   = tid >> 4;      // V: k-quad 0..31 (rows 4kq..4kq+3)
  const int dc8  = tid & 15;      // V: 8-float d chunk

  for (int it = 0; it < NITER; ++it) {
    const int k0 = it * BN;

    // ---- global loads + cvt to f16 (pre-barrier; overlaps other waves' PV) ----
    const float* kp = Kb + (long)(k0 + krow) * HD + kq4 * 32;
    int4 ks[4];
#pragma unroll
    for (int jj = 0; jj < 4; ++jj) {
      float4 e = ((const float4*)kp)[2 * jj];
      float4 o = ((const float4*)kp)[2 * jj + 1];
      ks[jj].x = (int)pkh(e.x, e.y);
      ks[jj].y = (int)pkh(e.z, e.w);
      ks[jj].z = (int)pkh(o.x, o.y);
      ks[jj].w = (int)pkh(o.z, o.w);
    }

    const float* vp = Vb + (long)(k0 + 4 * kq) * HD + dc8 * 8;
    float4 vr[4][2];
#pragma unroll
    for (int r = 0; r < 4; ++r) {
      vr[r][0] = ((const float4*)(vp + r * HD))[0];
      vr[r][1] = ((const float4*)(vp + r * HD))[1];
    }
    uint2 vs[8];
#pragma unroll
    for (int jd = 0; jd < 8; ++jd) {
      const int hsel = jd >> 2, e = jd & 3;
      float x0 = ((const float*)&vr[0][hsel])[e];
      float x1 = ((const float*)&vr[1][hsel])[e];
      float x2 = ((const float*)&vr[2][hsel])[e];
      float x3 = ((const float*)&vr[3][hsel])[e];
      vs[jd].x = pkh(x0, x1);
      vs[jd].y = pkh(x2, x3);
    }

    __syncthreads();  // (A) all waves done reading prev tile

    // K staging: 4 swizzled b128 stores
#pragma unroll
    for (int jj = 0; jj < 4; ++jj) {
      int j = kq4 * 4 + jj;
      int pos = j ^ (krow & 15);
      *(int4*)(kt_lds + krow * HD + pos * 8) = ks[jj];
    }
    // V^T staging: 8 swizzled b64 stores; chunk c8=kq>>1 (0..15)
#pragma unroll
    for (int jd = 0; jd < 8; ++jd) {
      int d = dc8 * 8 + jd;
      int sw3 = ((d >> 3) ^ d) & 7;
      int c8 = kq >> 1;
      int pos = (c8 & 8) | ((c8 & 7) ^ sw3);
      *(uint2*)(vt_lds + d * BN + pos * 8 + (kq & 1) * 4) = vs[jd];
    }

    __syncthreads();  // (B) staging visible

    // ---- two 64-k sub-tiles computed from the one staged 128-k tile ----
#pragma unroll
    for (int kh = 0; kh < 2; ++kh) {
      // S^T = K * Q^T (32x32x16): lane holds S[q=ml][k=kh*64+kt*32+(r&3)+8(r>>2)+4hi]
      f32x16 sacc[2];
      sacc[0] = (f32x16)(0.f);
      sacc[1] = (f32x16)(0.f);

#pragma unroll
      for (int dc = 0; dc < 8; ++dc) {
#pragma unroll
        for (int kt = 0; kt < 2; ++kt) {
          int row = kh * 64 + kt * 32 + ml;
          int pos = (2 * dc + hi) ^ (row & 15);
          f16x8 af = *(const f16x8*)(kt_lds + row * HD + pos * 8);
          sacc[kt] = __builtin_amdgcn_mfma_f32_32x32x16_f16(
              af, qf[dc], sacc[kt], 0, 0, 0);
        }
      }

      // ---- online softmax: one q-column per lane ----
      float x0 = fmaxf(sacc[0][0], sacc[1][0]);
      float x1 = fmaxf(sacc[0][1], sacc[1][1]);
      float x2 = fmaxf(sacc[0][2], sacc[1][2]);
      float x3 = fmaxf(sacc[0][3], sacc[1][3]);
#pragma unroll
      for (int r = 4; r < 16; r += 4) {
        x0 = fmaxf(x0, fmaxf(sacc[0][r + 0], sacc[1][r + 0]));
        x1 = fmaxf(x1, fmaxf(sacc[0][r + 1], sacc[1][r + 1]));
        x2 = fmaxf(x2, fmaxf(sacc[0][r + 2], sacc[1][r + 2]));
        x3 = fmaxf(x3, fmaxf(sacc[0][r + 3], sacc[1][r + 3]));
      }
      float mx = fmaxf(fmaxf(x0, x1), fmaxf(x2, x3));
      mx = fmaxf(mx, __shfl_xor(mx, 32, 64));  // cross-half reduce

      // defer-max: skip rescale when running max unchanged (alpha would be exactly 1)
      if (__any(mx > mst)) {
        float mnew = fmaxf(mst, mx);
        float alpha = __builtin_amdgcn_exp2f(K1 * (mst - mnew));
        mst = mnew;
        lst *= alpha;
#pragma unroll
        for (int dt = 0; dt < 4; ++dt)
          oacc[dt] *= alpha;
      }

      const float nm = -K1 * mst;
      float p0 = 0.f, p1 = 0.f, p2 = 0.f, p3 = 0.f;
#pragma unroll
      for (int kt = 0; kt < 2; ++kt) {
#pragma unroll
        for (int r = 0; r < 16; r += 4) {
          float e0 = __builtin_amdgcn_exp2f(fmaf(sacc[kt][r + 0], K1, nm));
          float e1 = __builtin_amdgcn_exp2f(fmaf(sacc[kt][r + 1], K1, nm));
          float e2 = __builtin_amdgcn_exp2f(fmaf(sacc[kt][r + 2], K1, nm));
          float e3 = __builtin_amdgcn_exp2f(fmaf(sacc[kt][r + 3], K1, nm));
          sacc[kt][r + 0] = e0; p0 += e0;
          sacc[kt][r + 1] = e1; p1 += e1;
          sacc[kt][r + 2] = e2; p2 += e2;
          sacc[kt][r + 3] = e3; p3 += e3;
        }
      }
      lst += (p0 + p1) + (p2 + p3);  // half-lane-partial l (reduced at epilogue)

      // ---- O^T += V^T * P^T (32x32x16), 4 k-steps of 16 ----
#pragma unroll
      for (int st = 0; st < 4; ++st) {
        const int kt = st >> 1;
        const int R  = 8 * (st & 1);
        // assemble B-frag: lane (q=ml,hi) needs k = kh*64 + st*16 + hi*8 + (0..7)
        unsigned pA0 = pkh(sacc[kt][R + 0], sacc[kt][R + 1]);
        unsigned pA1 = pkh(sacc[kt][R + 2], sacc[kt][R + 3]);
        unsigned pB0 = pkh(sacc[kt][R + 4], sacc[kt][R + 5]);
        unsigned pB1 = pkh(sacc[kt][R + 6], sacc[kt][R + 7]);
        unsigned s0 = hib ? pA0 : pB0;
        unsigned s1 = hib ? pA1 : pB1;
        unsigned r0 = (unsigned)__shfl_xor((int)s0, 32, 64);
        unsigned r1 = (unsigned)__shfl_xor((int)s1, 32, 64);
        int4 bf;
        bf.x = (int)(hib ? r0 : pA0);
        bf.y = (int)(hib ? r1 : pA1);
        bf.z = (int)(hib ? pB0 : r0);
        bf.w = (int)(hib ? pB1 : r1);
        f16x8 pfrag = __builtin_bit_cast(f16x8, bf);
#pragma unroll
        for (int dt = 0; dt < 4; ++dt) {
          int d = dt * 32 + ml;
          int sw3 = ((d >> 3) ^ d) & 7;
          int c8 = kh * 8 + 2 * st + hi;
          int pos = (c8 & 8) | ((c8 & 7) ^ sw3);
          f16x8 vf = *(const f16x8*)(vt_lds + d * BN + pos * 8);
          oacc[dt] = __builtin_amdgcn_mfma_f32_32x32x16_f16(
              vf, pfrag, oacc[dt], 0, 0, 0);
        }
      }
    }
  }

  // ---- epilogue: finish l across half-waves, normalize, float4 stores ----
  float lf = lst + __shfl_xor(lst, 32, 64);
  float linv = 1.0f / lf;
#pragma unroll
  for (int dt = 0; dt < 4; ++dt) {
#pragma unroll
    for (int t = 0; t < 4; ++t) {
      f32x4 ov;
      ov[0] = oacc[dt][4 * t + 0] * linv;
      ov[1] = oacc[dt][4 * t + 1] * linv;
      ov[2] = oacc[dt][4 * t + 2] * linv;
      ov[3] = oacc[dt][4 * t + 3] * linv;
      *(f32x4*)(Ow + ml * HD + dt * 32 + 8 * t + 4 * hi) = ov;
    }
  }
}

extern "C" void kernel_launch(void* const* d_in, const int* in_sizes, int n_in,
                              void* d_out, int out_size, void* d_ws, size_t ws_size,
                              hipStream_t stream) {
  const float* q = (const float*)d_in[0];
  const float* k = (const float*)d_in[1];
  const float* v = (const float*)d_in[2];
  float* o = (float*)d_out;
  fa_gqa_kernel<<<dim3(512), dim3(512), 0, stream>>>(q, k, v, o);
}

// Round 7
// 302.272 us; speedup vs baseline: 3.6959x; 1.0422x over previous
//
#include <hip/hip_runtime.h>

#define SEQ    2048
#define HD     128
#define BN     64
#define NITER  (SEQ / BN)
#define NKVH   16
#define TILE_E 8192   // f16 elements per 64x128 tile (16 KB)

typedef __fp16 f16x8  __attribute__((ext_vector_type(8)));
typedef float  f32x4  __attribute__((ext_vector_type(4)));
typedef float  f32x16 __attribute__((ext_vector_type(16)));

// pack two fp32 -> one uint of two f16 (RTZ)
__device__ __forceinline__ unsigned pkh(float a, float b) {
  auto h = __builtin_amdgcn_cvt_pkrtz(a, b);
  return __builtin_bit_cast(unsigned, h);
}

// direct HBM/L2 -> LDS DMA, 16 B per lane; lds dest wave-uniform base + lane*16
__device__ __forceinline__ void gl_lds16(const unsigned short* g, unsigned short* l) {
  __builtin_amdgcn_global_load_lds(
      (const __attribute__((address_space(1))) void*)g,
      (__attribute__((address_space(3))) void*)l, 16, 0, 0);
}

// ---------------------------------------------------------------------------
// Pass 1: K,V fp32 -> f16 tiles in workspace, PRE-SWIZZLED in the exact LDS
// byte layout of the main kernel (so main-kernel staging is a linear copy).
// K tile [64 k][128 d]: 16B chunk j at pos j ^ (row&15).
// V^T tile [128 d][64 k]: 16B chunk c8 at pos c8 ^ (((d>>3)^d)&7).
// Tiles are contiguous: head hh, tile t -> element offset (hh*32+t)*8192.
// ---------------------------------------------------------------------------
__global__ __launch_bounds__(256)
void cvt_kv(const float* __restrict__ K, const float* __restrict__ V,
            unsigned short* __restrict__ Kw, unsigned short* __restrict__ Vw)
{
  __shared__ unsigned short kt[TILE_E];
  __shared__ unsigned short vt[TILE_E];
  const int tid = threadIdx.x;
  const int T   = blockIdx.x;               // 0..511 = hh*32 + t
  const long base = (long)T * TILE_E;       // fp32 element offset (same count)

  // K staging (R0-verified arithmetic)
  const int krow = tid >> 2, kq4 = tid & 3;
  const float* kp = K + base + (long)krow * HD + kq4 * 32;
#pragma unroll
  for (int jj = 0; jj < 4; ++jj) {
    float4 e = ((const float4*)kp)[2 * jj];
    float4 o = ((const float4*)kp)[2 * jj + 1];
    int4 ksj;
    ksj.x = (int)pkh(e.x, e.y);
    ksj.y = (int)pkh(e.z, e.w);
    ksj.z = (int)pkh(o.x, o.y);
    ksj.w = (int)pkh(o.z, o.w);
    int j = kq4 * 4 + jj;
    int pos = j ^ (krow & 15);
    *(int4*)(kt + krow * HD + pos * 8) = ksj;
  }
  // V^T staging (R0-verified arithmetic)
  const int kq = tid >> 4, dc8 = tid & 15;
  const float* vp = V + base + (long)(4 * kq) * HD + dc8 * 8;
  float4 vr[4][2];
#pragma unroll
  for (int r = 0; r < 4; ++r) {
    vr[r][0] = ((const float4*)(vp + r * HD))[0];
    vr[r][1] = ((const float4*)(vp + r * HD))[1];
  }
#pragma unroll
  for (int jd = 0; jd < 8; ++jd) {
    const int hsel = jd >> 2, e = jd & 3;
    uint2 v2;
    v2.x = pkh(((const float*)&vr[0][hsel])[e], ((const float*)&vr[1][hsel])[e]);
    v2.y = pkh(((const float*)&vr[2][hsel])[e], ((const float*)&vr[3][hsel])[e]);
    int d = dc8 * 8 + jd;
    int sw3 = ((d >> 3) ^ d) & 7;
    int pos = (kq >> 1) ^ sw3;
    *(uint2*)(vt + d * 64 + pos * 8 + (kq & 1) * 4) = v2;
  }
  __syncthreads();
  // linear dump LDS -> workspace (coalesced dwordx4)
  int4* kd = (int4*)(Kw + (long)T * TILE_E);
  int4* vd = (int4*)(Vw + (long)T * TILE_E);
  const int4* ksrc = (const int4*)kt;
  const int4* vsrc = (const int4*)vt;
#pragma unroll
  for (int i = 0; i < 4; ++i) {
    kd[i * 256 + tid] = ksrc[i * 256 + tid];
    vd[i * 256 + tid] = vsrc[i * 256 + tid];
  }
}

// ---------------------------------------------------------------------------
// Pass 2: attention. Staging = zero-register global_load_lds byte-copy of
// pre-swizzled tiles; LDS double-buffered, ONE barrier per iteration.
// ---------------------------------------------------------------------------
__global__ __launch_bounds__(256, 2)
void fa_gqa_kernel(const float* __restrict__ Q,
                   const unsigned short* __restrict__ Kw,
                   const unsigned short* __restrict__ Vw,
                   float* __restrict__ O)
{
  __shared__ unsigned short kt_lds[2][TILE_E];
  __shared__ unsigned short vt_lds[2][TILE_E];

  const int tid  = threadIdx.x;
  const int lane = tid & 63;
  const int w    = tid >> 6;
  const int ml   = lane & 31;   // 32x32 MFMA row/col lane index
  const int hi   = lane >> 5;   // half-wave select
  const bool hib = (hi != 0);

  // XCD-clustered virtual block mapping (K/V L2 locality)
  const int F     = blockIdx.x;        // 0..1023
  const int xcd   = F & 7;
  const int s     = F >> 3;
  const int bh    = xcd * 8 + (s >> 4);
  const int qtile = s & 15;

  const int b = bh >> 5;
  const int h = bh & 31;
  const long qrow0 = (long)bh * SEQ + qtile * 128 + w * 32;
  const float* Qw = Q + qrow0 * HD;
  float*       Ow = O + qrow0 * HD;
  const int kvh = b * 8 + (h >> 2);

  // Q fragments (B-operand of 32x32x16: lane holds Q[q=w*32+ml][d=dc*16+hi*8+j])
  f16x8 qf[8];
#pragma unroll
  for (int dc = 0; dc < 8; ++dc) {
    const float4* qp = (const float4*)(Qw + ml * HD + dc * 16 + hi * 8);
    float4 a = qp[0], bq = qp[1];
    int4 t;
    t.x = (int)pkh(a.x, a.y);
    t.y = (int)pkh(a.z, a.w);
    t.z = (int)pkh(bq.x, bq.y);
    t.w = (int)pkh(bq.z, bq.w);
    qf[dc] = __builtin_bit_cast(f16x8, t);
  }

  // O^T accumulators: 4 d-tiles of 32x32; lane holds O[q=ml][d=dt*32+(r&3)+8(r>>2)+4hi]
  f32x16 oacc[4];
#pragma unroll
  for (int dt = 0; dt < 4; ++dt)
    oacc[dt] = (f32x16)(0.f);

  float mst = -1e30f;
  float lst = 0.f;

  const float K1 = 0.08838834764831845f * 1.4426950408889634f; // scale*log2(e)

  // staging: wave w copies quarter w (4 KB) of each tile; pre-swizzled source,
  // linear LDS dest (the legal global_load_lds pattern)
  const unsigned short* kwb = Kw + (long)kvh * NITER * TILE_E;
  const unsigned short* vwb = Vw + (long)kvh * NITER * TILE_E;
  const int woff = w * 2048;  // elements = 4 KB

  // prologue: issue tile 0 into buf 0
  {
    const unsigned short* ks = kwb + woff + lane * 8;
    const unsigned short* vs = vwb + woff + lane * 8;
#pragma unroll
    for (int c = 0; c < 4; ++c) {
      gl_lds16(ks + c * 512, &kt_lds[0][woff + c * 512]);
      gl_lds16(vs + c * 512, &vt_lds[0][woff + c * 512]);
    }
  }

  for (int it = 0; it < NITER; ++it) {
    const int cur = it & 1;
    // implicit vmcnt(0)+lgkmcnt(0) drain before s_barrier: buf[cur] DMA complete
    // in every wave, and all waves are done reading buf[cur^1]
    __syncthreads();

    // issue NEXT tile's DMA into buf[cur^1]; waits at the NEXT barrier,
    // i.e. the loads have the whole compute phase in flight
    if (it + 1 < NITER) {
      const unsigned short* ks = kwb + (long)(it + 1) * TILE_E + woff + lane * 8;
      const unsigned short* vs = vwb + (long)(it + 1) * TILE_E + woff + lane * 8;
      const int nxt = cur ^ 1;
#pragma unroll
      for (int c = 0; c < 4; ++c) {
        gl_lds16(ks + c * 512, &kt_lds[nxt][woff + c * 512]);
        gl_lds16(vs + c * 512, &vt_lds[nxt][woff + c * 512]);
      }
    }

    // ---- S^T = K * Q^T (32x32x16): lane holds S[q=ml][k=kt*32+(r&3)+8(r>>2)+4hi] ----
    f32x16 sacc[2];
    sacc[0] = (f32x16)(0.f);
    sacc[1] = (f32x16)(0.f);

#pragma unroll
    for (int dc = 0; dc < 8; ++dc) {
#pragma unroll
      for (int kt = 0; kt < 2; ++kt) {
        int row = kt * 32 + ml;
        int pos = (2 * dc + hi) ^ (row & 15);
        f16x8 af = *(const f16x8*)(kt_lds[cur] + row * HD + pos * 8);
        sacc[kt] = __builtin_amdgcn_mfma_f32_32x32x16_f16(
            af, qf[dc], sacc[kt], 0, 0, 0);
      }
    }

    // ---- online softmax: one q-column per lane ----
    float x0 = fmaxf(sacc[0][0], sacc[1][0]);
    float x1 = fmaxf(sacc[0][1], sacc[1][1]);
    float x2 = fmaxf(sacc[0][2], sacc[1][2]);
    float x3 = fmaxf(sacc[0][3], sacc[1][3]);
#pragma unroll
    for (int r = 4; r < 16; r += 4) {
      x0 = fmaxf(x0, fmaxf(sacc[0][r + 0], sacc[1][r + 0]));
      x1 = fmaxf(x1, fmaxf(sacc[0][r + 1], sacc[1][r + 1]));
      x2 = fmaxf(x2, fmaxf(sacc[0][r + 2], sacc[1][r + 2]));
      x3 = fmaxf(x3, fmaxf(sacc[0][r + 3], sacc[1][r + 3]));
    }
    float mx = fmaxf(fmaxf(x0, x1), fmaxf(x2, x3));
    mx = fmaxf(mx, __shfl_xor(mx, 32, 64));  // cross-half reduce

    // defer-max: skip rescale when running max unchanged (alpha would be exactly 1)
    if (__any(mx > mst)) {
      float mnew = fmaxf(mst, mx);
      float alpha = __builtin_amdgcn_exp2f(K1 * (mst - mnew));
      mst = mnew;
      lst *= alpha;
#pragma unroll
      for (int dt = 0; dt < 4; ++dt)
        oacc[dt] *= alpha;
    }

    const float nm = -K1 * mst;
    float p0 = 0.f, p1 = 0.f, p2 = 0.f, p3 = 0.f;
#pragma unroll
    for (int kt = 0; kt < 2; ++kt) {
#pragma unroll
      for (int r = 0; r < 16; r += 4) {
        float e0 = __builtin_amdgcn_exp2f(fmaf(sacc[kt][r + 0], K1, nm));
        float e1 = __builtin_amdgcn_exp2f(fmaf(sacc[kt][r + 1], K1, nm));
        float e2 = __builtin_amdgcn_exp2f(fmaf(sacc[kt][r + 2], K1, nm));
        float e3 = __builtin_amdgcn_exp2f(fmaf(sacc[kt][r + 3], K1, nm));
        sacc[kt][r + 0] = e0; p0 += e0;
        sacc[kt][r + 1] = e1; p1 += e1;
        sacc[kt][r + 2] = e2; p2 += e2;
        sacc[kt][r + 3] = e3; p3 += e3;
      }
    }
    lst += (p0 + p1) + (p2 + p3);  // half-lane-partial l (reduced at epilogue)

    // ---- O^T += V^T * P^T (32x32x16), 4 k-steps of 16 ----
#pragma unroll
    for (int st = 0; st < 4; ++st) {
      const int kt = st >> 1;
      const int R  = 8 * (st & 1);
      // assemble B-frag: lane (q=ml,hi) needs k = st*16 + hi*8 + (0..7)
      unsigned pA0 = pkh(sacc[kt][R + 0], sacc[kt][R + 1]);
      unsigned pA1 = pkh(sacc[kt][R + 2], sacc[kt][R + 3]);
      unsigned pB0 = pkh(sacc[kt][R + 4], sacc[kt][R + 5]);
      unsigned pB1 = pkh(sacc[kt][R + 6], sacc[kt][R + 7]);
      unsigned s0 = hib ? pA0 : pB0;
      unsigned s1 = hib ? pA1 : pB1;
      unsigned r0 = (unsigned)__shfl_xor((int)s0, 32, 64);
      unsigned r1 = (unsigned)__shfl_xor((int)s1, 32, 64);
      int4 bf;
      bf.x = (int)(hib ? r0 : pA0);
      bf.y = (int)(hib ? r1 : pA1);
      bf.z = (int)(hib ? pB0 : r0);
      bf.w = (int)(hib ? pB1 : r1);
      f16x8 pfrag = __builtin_bit_cast(f16x8, bf);
#pragma unroll
      for (int dt = 0; dt < 4; ++dt) {
        int d = dt * 32 + ml;
        int pos = (2 * st + hi) ^ (((d >> 3) ^ d) & 7);
        f16x8 vf = *(const f16x8*)(vt_lds[cur] + d * 64 + pos * 8);
        oacc[dt] = __builtin_amdgcn_mfma_f32_32x32x16_f16(
            vf, pfrag, oacc[dt], 0, 0, 0);
      }
    }
  }

  // ---- epilogue: finish l across half-waves, normalize, float4 stores ----
  float lf = lst + __shfl_xor(lst, 32, 64);
  float linv = 1.0f / lf;
#pragma unroll
  for (int dt = 0; dt < 4; ++dt) {
#pragma unroll
    for (int t = 0; t < 4; ++t) {
      f32x4 ov;
      ov[0] = oacc[dt][4 * t + 0] * linv;
      ov[1] = oacc[dt][4 * t + 1] * linv;
      ov[2] = oacc[dt][4 * t + 2] * linv;
      ov[3] = oacc[dt][4 * t + 3] * linv;
      *(f32x4*)(Ow + ml * HD + dt * 32 + 8 * t + 4 * hi) = ov;
    }
  }
}

extern "C" void kernel_launch(void* const* d_in, const int* in_sizes, int n_in,
                              void* d_out, int out_size, void* d_ws, size_t ws_size,
                              hipStream_t stream) {
  const float* q = (const float*)d_in[0];
  const float* k = (const float*)d_in[1];
  const float* v = (const float*)d_in[2];
  float* o = (float*)d_out;
  // workspace: Kw (8.39 MB) + Vw (8.39 MB) f16 pre-swizzled tiles
  unsigned short* Kw = (unsigned short*)d_ws;
  unsigned short* Vw = Kw + (long)NKVH * NITER * TILE_E;
  cvt_kv<<<dim3(NKVH * NITER), dim3(256), 0, stream>>>(k, v, Kw, Vw);
  fa_gqa_kernel<<<dim3(1024), dim3(256), 0, stream>>>(q, Kw, Vw, o);
}